// Round 2
// baseline (187.315 us; speedup 1.0000x reference)
//
#include <hip/hip_runtime.h>
#include <hip/hip_bf16.h>

typedef __attribute__((ext_vector_type(8))) short short8;
typedef __attribute__((ext_vector_type(4))) float f32x4;

__device__ __forceinline__ unsigned short f2bf(float x) {
    unsigned int u = __float_as_uint(x);
    unsigned int lsb = (u >> 16) & 1u;
    u += 0x7fffu + lsb;                    // round-to-nearest-even
    return (unsigned short)(u >> 16);
}

__device__ __forceinline__ short8 pack8(f32x4 a, f32x4 b) {
    short8 r;
    r[0] = (short)f2bf(a.x); r[1] = (short)f2bf(a.y);
    r[2] = (short)f2bf(a.z); r[3] = (short)f2bf(a.w);
    r[4] = (short)f2bf(b.x); r[5] = (short)f2bf(b.y);
    r[6] = (short)f2bf(b.z); r[7] = (short)f2bf(b.w);
    return r;
}

// Standalone init (fallback path): out[n][c] = bias[c]
__global__ __launch_bounds__(256) void k_init(const float* __restrict__ bias,
                                              float* __restrict__ out, long total4) {
    long i4 = (long)blockIdx.x * 256 + threadIdx.x;
    if (i4 < total4) {
        const f32x4* b4 = (const f32x4*)bias;
        ((f32x4*)out)[i4] = b4[i4 & 15];
    }
}

// Fused: blocks [0,gblocks) compute G = (feat @ W.T) in bf16 via MFMA;
// blocks [gblocks, ...) broadcast bias into out.
// R10: G is stored as 4 contiguous FEATURE PLANES of 16 features each:
//   G[fg][row][f] at fg*(N*16) + row*16 + f   (ushort units)
// so each plane is 3.2 MB (< 4 MiB per-XCD L2) and k_spmm's XCD-partitioned
// gathers stay L2-local. ct (the MFMA col-tile index) IS fg.
// NOTE: out init must be a PLAIN store — NT store streamed it to HBM and made
// every later atomic flush RMW against HBM (R4: WRITE_SIZE doubled, +22 us).
__global__ __launch_bounds__(256) void k_setup(const float* __restrict__ feat,
                                               const float* __restrict__ W,
                                               const float* __restrict__ bias,
                                               unsigned short* __restrict__ G,
                                               float* __restrict__ out,
                                               int N, int gblocks) {
    if ((int)blockIdx.x >= gblocks) {
        long i4 = (long)(blockIdx.x - gblocks) * 256 + threadIdx.x;
        long total4 = (long)N * 16;            // N*64 floats / 4
        if (i4 < total4) {
            const f32x4* b4 = (const f32x4*)bias;
            ((f32x4*)out)[i4] = b4[i4 & 15];   // plain store: stay dirty in L2
        }
        return;
    }

    int wave = blockIdx.x * 4 + (threadIdx.x >> 6);
    int lane = threadIdx.x & 63;
    int m0 = wave * 16;
    if (m0 >= N) return;
    int n = lane & 15;
    int quad = lane >> 4;

    // B fragments: B[k][c0+n] = W[c0+n][k]; k = ks*32 + quad*8 + j
    short8 bf[4][2];
#pragma unroll
    for (int ct = 0; ct < 4; ++ct)
#pragma unroll
        for (int ks = 0; ks < 2; ++ks) {
            const f32x4* wp = (const f32x4*)(W + (size_t)(ct * 16 + n) * 64 + ks * 32 + quad * 8);
            f32x4 w0 = wp[0];
            f32x4 w1 = wp[1];
            bf[ct][ks] = pack8(w0, w1);
        }

    // A fragments: A[m0+n][k]  (NT load: feat read exactly once)
    int mrow = m0 + n; if (mrow >= N) mrow = N - 1;
    short8 af[2];
#pragma unroll
    for (int ks = 0; ks < 2; ++ks) {
        const f32x4* ap = (const f32x4*)(feat + (size_t)mrow * 64 + ks * 32 + quad * 8);
        f32x4 a0 = __builtin_nontemporal_load(ap);
        f32x4 a1 = __builtin_nontemporal_load(ap + 1);
        af[ks] = pack8(a0, a1);
    }

    f32x4 acc[4];
#pragma unroll
    for (int ct = 0; ct < 4; ++ct) {
        acc[ct] = (f32x4){0.f, 0.f, 0.f, 0.f};
#pragma unroll
        for (int ks = 0; ks < 2; ++ks)
            acc[ct] = __builtin_amdgcn_mfma_f32_16x16x32_bf16(af[ks], bf[ct][ks], acc[ct], 0, 0, 0);
    }

    // D layout: col = lane&15 (=n), row = quad*4 + reg. Plane-major store:
    // per (ct,r) the 16 lanes write 32 contiguous bytes of plane ct.
    size_t pstride = (size_t)N * 16;
#pragma unroll
    for (int ct = 0; ct < 4; ++ct)
#pragma unroll
        for (int r = 0; r < 4; ++r) {
            int rowm = m0 + quad * 4 + r;
            if (rowm < N)
                G[(size_t)ct * pstride + (size_t)rowm * 16 + n] = f2bf(acc[ct][r]);
        }
}

// SpMM: out[row] += val * G[col]. Sorted rows.
// R10: XCD-partitioned feature planes. R1 proved the kernel is bound by the
// random-gather service rate (same time at 1/4 the gather instructions,
// FETCH unchanged): G (12.8 MB) >> 4 MiB per-XCD L2, so gathers miss local
// L2 and saturate the EA/L3 path (~1.25 TB/s random). Now each XCD pair
// owns one 3.2 MB 16-feature plane (fg = (blockIdx&7)>>1, using the
// round-robin block->XCD mapping) and processes ALL edges for those 16
// features -> gathers are local-L2 hits. Metadata is read 4x (streamed, NT).
// Per wave: 128 edges, 32 packs of 4 edges; lane = (q = edge-in-pack) x
// (fb = feature). Pack gathers (ushort) all issued up front; cols/vals via
// ds_bpermute; wave-uniform row-boundary logic (rows sorted) with vector
// masking inside split packs. Flush: 2x shfl_xor quarter-reduce, lanes 0-15
// write one 64B line of out (plain store bias+acc for interior rows,
// atomicAdd for first/last possibly-shared rows) — each fg owns whole 64B
// lines, no cross-XCD false sharing.
__global__ __launch_bounds__(256) void k_spmm(const unsigned short* __restrict__ G,
                                              const int* __restrict__ erow,
                                              const int* __restrict__ ecol,
                                              const float* __restrict__ evalv,
                                              const float* __restrict__ bias,
                                              float* __restrict__ out, int E, int N) {
    int b = blockIdx.x;
    int fg  = (b & 7) >> 1;                 // XCD pair -> feature group
    int sub = (b >> 3) * 2 + (b & 1);       // block index within this fg
    int wavein = threadIdx.x >> 6;
    int lane = threadIdx.x & 63;
    long base0 = ((long)sub * 4 + wavein) * 128;
    if (base0 >= E) return;

    int fb = lane & 15;                     // feature within group
    int q  = lane >> 4;                     // edge slot within 4-edge pack
    const unsigned short* plane = G + (size_t)fg * ((size_t)N * 16);
    float blane = bias[fg * 16 + fb];

    float acc = 0.f;
    bool first = true;                      // first row may be shared w/ prev wave
    int cur;

    auto flush = [&](bool atomic_path) {
        float t = acc + __shfl_xor(acc, 16);
        t += __shfl_xor(t, 32);
        if (lane < 16) {
            float* p = out + ((size_t)(unsigned)cur << 6) + (unsigned)(fg * 16 + lane);
            if (atomic_path) atomicAdd(p, t);
            else *p = blane + t;
        }
        acc = 0.f;
    };

    if (base0 + 128 <= E) {
        // ---- fast path: full 128-edge segment ----
        long i0 = base0 + lane;
        int rv[2], cv[2], vv[2];
        rv[0] = __builtin_nontemporal_load(erow + i0);
        cv[0] = __builtin_nontemporal_load(ecol + i0);
        vv[0] = __builtin_nontemporal_load((const int*)evalv + i0);
        rv[1] = __builtin_nontemporal_load(erow + i0 + 64);
        cv[1] = __builtin_nontemporal_load(ecol + i0 + 64);
        vv[1] = __builtin_nontemporal_load((const int*)evalv + i0 + 64);

        cur = __builtin_amdgcn_readlane(rv[0], 0);

        int vq4 = q << 2;                   // bpermute byte index of this quarter

        // issue all 32 pack-gathers up front (L2-local, ushort each)
        unsigned short gbuf[32];
#pragma unroll
        for (int k = 0; k < 32; ++k) {
            int c = __builtin_amdgcn_ds_bpermute(vq4 + 16 * (k & 15), cv[k >> 4]);
            gbuf[k] = plane[(size_t)(unsigned)c * 16 + fb];
        }
        __builtin_amdgcn_sched_barrier(0);  // keep loads ahead of consume

#pragma unroll
        for (int k = 0; k < 32; ++k) {
            int ch = k >> 4;
            int i4 = (k & 15) * 4;
            int r0 = __builtin_amdgcn_readlane(rv[ch], i4);
            int r3 = __builtin_amdgcn_readlane(rv[ch], i4 + 3);
            float vs = __int_as_float(__builtin_amdgcn_ds_bpermute(vq4 + i4 * 4, vv[ch]));
            float f = __uint_as_float((unsigned)gbuf[k] << 16);

            if (r0 == r3) {
                // whole pack in one row (common: avg row length 16)
                if (r0 != cur) { flush(first); first = false; cur = r0; }
                acc = fmaf(vs, f, acc);
            } else {
                // row boundary inside pack: iterate distinct rows, vector-mask
                int rowsv = __builtin_amdgcn_ds_bpermute(vq4 + i4 * 4, rv[ch]);
                int r1 = __builtin_amdgcn_readlane(rv[ch], i4 + 1);
                int r2 = __builtin_amdgcn_readlane(rv[ch], i4 + 2);
                int rr = r0;
                while (true) {
                    if (rr != cur) { flush(first); first = false; cur = rr; }
                    float vm = (rowsv == rr) ? vs : 0.f;
                    acc = fmaf(vm, f, acc);
                    if (rr == r3) break;
                    rr = (r1 > rr) ? r1 : ((r2 > rr) ? r2 : r3);
                }
            }
        }
    } else {
        // ---- tail path: generic per-edge loop ----
        cur = erow[base0];
        for (long e = base0; e < (long)E; ++e) {
            int r = erow[e];
            int c = ecol[e];
            float v = evalv[e];
            float f = __uint_as_float((unsigned)plane[(size_t)(unsigned)c * 16 + fb] << 16);
            if (r != cur) { flush(first); first = false; cur = r; }
            float vm = (q == 0) ? v : 0.f;  // only quarter 0 accumulates
            acc = fmaf(vm, f, acc);
        }
    }

    // last row may be shared with the next wave -> always atomic
    flush(true);
}

// Fallback if ws too small: fused f32 gather + shfl transform at flush.
__global__ __launch_bounds__(256) void k_fused(const float* __restrict__ feat,
                                               const int* __restrict__ erow,
                                               const int* __restrict__ ecol,
                                               const float* __restrict__ evalv,
                                               const float* __restrict__ W,
                                               float* __restrict__ out,
                                               int E, int epw) {
    __shared__ float Wt[64 * 64];
    for (int i = threadIdx.x; i < 4096; i += 256) {
        int c = i >> 6, f = i & 63;
        Wt[f * 64 + c] = W[i];
    }
    __syncthreads();

    int wave = blockIdx.x * 4 + (threadIdx.x >> 6);
    int lane = threadIdx.x & 63;
    long e0 = (long)wave * epw;
    if (e0 >= E) return;
    long e1 = e0 + epw; if (e1 > E) e1 = E;

    int cur = erow[e0];
    float acc = 0.f;
    for (long e = e0; e < e1; ++e) {
        int r = erow[e];
        int c = ecol[e];
        float v = evalv[e];
        float g = feat[((size_t)c << 6) | lane];
        if (r != cur) {
            float res = 0.f;
#pragma unroll
            for (int f = 0; f < 64; ++f)
                res += __shfl(acc, f, 64) * Wt[f * 64 + lane];
            atomicAdd(out + ((size_t)cur << 6) + lane, res);
            acc = 0.f;
            cur = r;
        }
        acc += v * g;
    }
    {
        float res = 0.f;
#pragma unroll
        for (int f = 0; f < 64; ++f)
            res += __shfl(acc, f, 64) * Wt[f * 64 + lane];
        atomicAdd(out + ((size_t)cur << 6) + lane, res);
    }
}

extern "C" void kernel_launch(void* const* d_in, const int* in_sizes, int n_in,
                              void* d_out, int out_size, void* d_ws, size_t ws_size,
                              hipStream_t stream) {
    const float* feat  = (const float*)d_in[0];
    const int*   erow  = (const int*)d_in[1];
    const int*   ecol  = (const int*)d_in[2];
    const float* evalv = (const float*)d_in[3];
    const float* W     = (const float*)d_in[4];
    const float* bias  = (const float*)d_in[5];
    float* out = (float*)d_out;

    int N = in_sizes[0] / 64;
    int E = in_sizes[1];

    size_t need = (size_t)N * 64 * sizeof(unsigned short);
    if (ws_size >= need) {
        unsigned short* G = (unsigned short*)d_ws;
        int tiles = (N + 15) / 16;
        int gblocks = (tiles + 3) / 4;
        long total4 = (long)N * 16;
        int iblocks = (int)((total4 + 255) / 256);
        k_setup<<<gblocks + iblocks, 256, 0, stream>>>(feat, W, bias, G, out, N, gblocks);

        // 4 feature-groups x (E/128) waves; 8-block octets map 2 blocks to
        // each XCD pair so every fg's plane stays in one XCD pair's L2.
        int nwpf = (E + 127) / 128;        // waves per feature-group
        int bpf  = (nwpf + 3) / 4;         // blocks per feature-group
        int noct = (bpf + 1) / 2;          // groups of 8 blocks
        k_spmm<<<noct * 8, 256, 0, stream>>>(G, erow, ecol, evalv, bias, out, E, N);
    } else {
        long total4 = (long)N * 16;
        k_init<<<(int)((total4 + 255) / 256), 256, 0, stream>>>(bias, out, total4);
        int epw = (E + 8191) / 8192;
        if (epw < 32) epw = 32;
        int nwaves = (E + epw - 1) / epw;
        int nblocks = (nwaves + 3) / 4;
        k_fused<<<nblocks, 256, 0, stream>>>(feat, erow, ecol, evalv, W, out, E, epw);
    }
}

// Round 3
// 173.711 us; speedup vs baseline: 1.0783x; 1.0783x over previous
//
#include <hip/hip_runtime.h>
#include <hip/hip_bf16.h>

typedef __attribute__((ext_vector_type(8))) short short8;
typedef __attribute__((ext_vector_type(4))) float f32x4;

__device__ __forceinline__ unsigned short f2bf(float x) {
    unsigned int u = __float_as_uint(x);
    unsigned int lsb = (u >> 16) & 1u;
    u += 0x7fffu + lsb;                    // round-to-nearest-even
    return (unsigned short)(u >> 16);
}

__device__ __forceinline__ short8 pack8(f32x4 a, f32x4 b) {
    short8 r;
    r[0] = (short)f2bf(a.x); r[1] = (short)f2bf(a.y);
    r[2] = (short)f2bf(a.z); r[3] = (short)f2bf(a.w);
    r[4] = (short)f2bf(b.x); r[5] = (short)f2bf(b.y);
    r[6] = (short)f2bf(b.z); r[7] = (short)f2bf(b.w);
    return r;
}

// Standalone init (fallback path): out[n][c] = bias[c]
__global__ __launch_bounds__(256) void k_init(const float* __restrict__ bias,
                                              float* __restrict__ out, long total4) {
    long i4 = (long)blockIdx.x * 256 + threadIdx.x;
    if (i4 < total4) {
        const f32x4* b4 = (const f32x4*)bias;
        ((f32x4*)out)[i4] = b4[i4 & 15];
    }
}

// Fused: blocks [0,gblocks) compute G = (feat @ W.T) in bf16 via MFMA;
// blocks [gblocks, ...) broadcast bias into out.
// G stored as 4 contiguous FEATURE PLANES of 16 features each:
//   G[fg][row][f] at fg*(N*16) + row*16 + f   (ushort units)
// -> each plane is 3.2 MB (< 4 MiB per-XCD L2), k_spmm gathers stay L2-local.
// NOTE: out init must be a PLAIN store — NT store streamed it to HBM and made
// every later atomic flush RMW against HBM (R4: WRITE_SIZE doubled, +22 us).
__global__ __launch_bounds__(256) void k_setup(const float* __restrict__ feat,
                                               const float* __restrict__ W,
                                               const float* __restrict__ bias,
                                               unsigned short* __restrict__ G,
                                               float* __restrict__ out,
                                               int N, int gblocks) {
    if ((int)blockIdx.x >= gblocks) {
        long i4 = (long)(blockIdx.x - gblocks) * 256 + threadIdx.x;
        long total4 = (long)N * 16;            // N*64 floats / 4
        if (i4 < total4) {
            const f32x4* b4 = (const f32x4*)bias;
            ((f32x4*)out)[i4] = b4[i4 & 15];   // plain store: stay dirty in L2
        }
        return;
    }

    int wave = blockIdx.x * 4 + (threadIdx.x >> 6);
    int lane = threadIdx.x & 63;
    int m0 = wave * 16;
    if (m0 >= N) return;
    int n = lane & 15;
    int quad = lane >> 4;

    // B fragments: B[k][c0+n] = W[c0+n][k]; k = ks*32 + quad*8 + j
    short8 bf[4][2];
#pragma unroll
    for (int ct = 0; ct < 4; ++ct)
#pragma unroll
        for (int ks = 0; ks < 2; ++ks) {
            const f32x4* wp = (const f32x4*)(W + (size_t)(ct * 16 + n) * 64 + ks * 32 + quad * 8);
            f32x4 w0 = wp[0];
            f32x4 w1 = wp[1];
            bf[ct][ks] = pack8(w0, w1);
        }

    // A fragments: A[m0+n][k]  (NT load: feat read exactly once)
    int mrow = m0 + n; if (mrow >= N) mrow = N - 1;
    short8 af[2];
#pragma unroll
    for (int ks = 0; ks < 2; ++ks) {
        const f32x4* ap = (const f32x4*)(feat + (size_t)mrow * 64 + ks * 32 + quad * 8);
        f32x4 a0 = __builtin_nontemporal_load(ap);
        f32x4 a1 = __builtin_nontemporal_load(ap + 1);
        af[ks] = pack8(a0, a1);
    }

    f32x4 acc[4];
#pragma unroll
    for (int ct = 0; ct < 4; ++ct) {
        acc[ct] = (f32x4){0.f, 0.f, 0.f, 0.f};
#pragma unroll
        for (int ks = 0; ks < 2; ++ks)
            acc[ct] = __builtin_amdgcn_mfma_f32_16x16x32_bf16(af[ks], bf[ct][ks], acc[ct], 0, 0, 0);
    }

    // D layout: col = lane&15 (=n), row = quad*4 + reg. Plane-major store:
    // per (ct,r) the 16 lanes write 32 contiguous bytes of plane ct.
    size_t pstride = (size_t)N * 16;
#pragma unroll
    for (int ct = 0; ct < 4; ++ct)
#pragma unroll
        for (int r = 0; r < 4; ++r) {
            int rowm = m0 + quad * 4 + r;
            if (rowm < N)
                G[(size_t)ct * pstride + (size_t)rowm * 16 + n] = f2bf(acc[ct][r]);
        }
}

// SpMM: out[row] += val * G[col]. Sorted rows.
// R11: L2-local planes (kept from R2) + duty-cycle fix. R2 evidence: 75 G
// seg/s achieved L2-local (vs 47 G mixed) but consume-phase control (readlane
// pairs, branches, flush) left waves issuing no gathers ~60% of the time.
// Now: (1) all 256-edge-segment metadata preloaded (12 NT loads, no loads in
// steady loop); (2) gathers pipelined one 8-gather group ahead, double-
// buffered, sched_barrier pins issue before consume -> a full gather window
// is in flight through every consume phase; (3) per-64-edge ballot boundary
// mask in SGPRs: interior packs (~94%) consume with just bpermute(vs)+fmaf,
// no readlanes/row-branches; R2's slow path only at true boundaries.
// Flush: 2x shfl_xor quarter-reduce, lanes 0-15 write one 64B line of out
// (plain store bias+acc interior, atomicAdd for first/last shared rows).
// Each fg owns distinct 64B lines of out -> no cross-fg interference.
__global__ __launch_bounds__(256) void k_spmm(const unsigned short* __restrict__ G,
                                              const int* __restrict__ erow,
                                              const int* __restrict__ ecol,
                                              const float* __restrict__ evalv,
                                              const float* __restrict__ bias,
                                              float* __restrict__ out, int E, int N) {
    int b = blockIdx.x;
    int fg  = (b & 7) >> 1;                 // XCD pair -> feature group
    int sub = (b >> 3) * 2 + (b & 1);       // block index within this fg
    int wavein = threadIdx.x >> 6;
    int lane = threadIdx.x & 63;
    long base0 = ((long)sub * 4 + wavein) * 256;
    if (base0 >= E) return;

    int fb = lane & 15;                     // feature within group
    int q  = lane >> 4;                     // edge slot within 4-edge pack
    int vq4 = q << 2;                       // bpermute byte base for quarter
    const unsigned short* plane = G + (size_t)fg * ((size_t)N * 16);
    float blane = bias[fg * 16 + fb];

    float acc = 0.f;
    bool first = true;                      // first row may be shared w/ prev wave
    int cur;

    auto flush = [&](bool atomic_path) {
        float t = acc + __shfl_xor(acc, 16);
        t += __shfl_xor(t, 32);
        if (lane < 16) {
            float* p = out + ((size_t)(unsigned)cur << 6) + (unsigned)(fg * 16 + lane);
            if (atomic_path) atomicAdd(p, t);
            else *p = blane + t;
        }
        acc = 0.f;
    };

    if (base0 + 256 <= E) {
        // ---- fast path: full 256-edge segment ----
        long i0 = base0 + lane;
        int rv[4], cv[4], vv[4];
#pragma unroll
        for (int c = 0; c < 4; ++c) {
            rv[c] = __builtin_nontemporal_load(erow + i0 + 64 * c);
            cv[c] = __builtin_nontemporal_load(ecol + i0 + 64 * c);
            vv[c] = __builtin_nontemporal_load((const int*)evalv + i0 + 64 * c);
        }
        cur = __builtin_amdgcn_readlane(rv[0], 0);

        // boundary masks: bit e of bm[c] = row[e] != row[e+1] (within chunk c;
        // bit 63 = boundary to next chunk / forced at segment end)
        unsigned long long bm[4];
#pragma unroll
        for (int c = 0; c < 4; ++c) {
            int rn = __shfl_down(rv[c], 1);
            unsigned long long m = __ballot(rv[c] != rn) & 0x7fffffffffffffffULL;
            int r63 = __builtin_amdgcn_readlane(rv[c], 63);
            int n0  = (c < 3) ? __builtin_amdgcn_readlane(rv[c + 1], 0) : (r63 + 1);
            if (r63 != n0) m |= 0x8000000000000000ULL;
            bm[c] = m;
        }

        unsigned gbuf[2][8];                // gather double buffer (8 packs/group)
        // prologue: issue group 0 (packs 0..7 = chunk 0, first half)
#pragma unroll
        for (int k = 0; k < 8; ++k) {
            int c0 = __builtin_amdgcn_ds_bpermute(vq4 + 16 * k, cv[0]);
            gbuf[0][k] = plane[(size_t)(unsigned)c0 * 16 + fb];
        }

        bool prevb = false;                 // boundary carried across chunks
#pragma unroll
        for (int g = 0; g < 8; ++g) {
            // issue group g+1 (8 pack-gathers) before consuming group g
            if (g < 7) {
                const int cn = (g + 1) >> 1;
#pragma unroll
                for (int k = 0; k < 8; ++k) {
                    const int pj = ((g + 1) & 1) * 8 + k;     // pack-in-chunk
                    int cc = __builtin_amdgcn_ds_bpermute(vq4 + 16 * pj, cv[cn]);
                    gbuf[(g + 1) & 1][k] = plane[(size_t)(unsigned)cc * 16 + fb];
                }
            }
            __builtin_amdgcn_sched_barrier(0);   // keep issue ahead of consume

#pragma unroll
            for (int k = 0; k < 8; ++k) {
                const int p  = g * 8 + k;   // pack index 0..63
                const int c  = p >> 4;      // chunk
                const int j  = p & 15;      // pack within chunk
                const int i4 = j * 4;       // first edge-lane of pack in chunk
                float vs = __int_as_float(__builtin_amdgcn_ds_bpermute(vq4 + i4 * 4, vv[c]));
                float f  = __uint_as_float(gbuf[g & 1][k] << 16);
                bool slow = (j == 0) ? (prevb || (bm[c] & 7ULL) != 0)
                                     : (((bm[c] >> (4 * j - 1)) & 0xFULL) != 0);
                if (!slow) {
                    acc = fmaf(vs, f, acc);             // whole pack in cur row
                } else {
                    int r0 = __builtin_amdgcn_readlane(rv[c], i4);
                    int r3 = __builtin_amdgcn_readlane(rv[c], i4 + 3);
                    if (r0 == r3) {
                        if (r0 != cur) { flush(first); first = false; cur = r0; }
                        acc = fmaf(vs, f, acc);
                    } else {
                        int rowsv = __builtin_amdgcn_ds_bpermute(vq4 + i4 * 4, rv[c]);
                        int r1 = __builtin_amdgcn_readlane(rv[c], i4 + 1);
                        int r2 = __builtin_amdgcn_readlane(rv[c], i4 + 2);
                        int rr = r0;
                        while (true) {
                            if (rr != cur) { flush(first); first = false; cur = rr; }
                            float vm = (rowsv == rr) ? vs : 0.f;
                            acc = fmaf(vm, f, acc);
                            if (rr == r3) break;
                            rr = (r1 > rr) ? r1 : ((r2 > rr) ? r2 : r3);
                        }
                    }
                }
                if (j == 15 && p < 63) prevb = ((bm[c] >> 63) & 1ULL) != 0;
            }
        }
    } else {
        // ---- tail path: generic per-edge loop ----
        cur = erow[base0];
        for (long e = base0; e < (long)E; ++e) {
            int r = erow[e];
            int c = ecol[e];
            float v = evalv[e];
            float f = __uint_as_float((unsigned)plane[(size_t)(unsigned)c * 16 + fb] << 16);
            if (r != cur) { flush(first); first = false; cur = r; }
            float vm = (q == 0) ? v : 0.f;  // only quarter 0 accumulates
            acc = fmaf(vm, f, acc);
        }
    }

    // last row may be shared with the next wave -> always atomic
    flush(true);
}

// Fallback if ws too small: fused f32 gather + shfl transform at flush.
__global__ __launch_bounds__(256) void k_fused(const float* __restrict__ feat,
                                               const int* __restrict__ erow,
                                               const int* __restrict__ ecol,
                                               const float* __restrict__ evalv,
                                               const float* __restrict__ W,
                                               float* __restrict__ out,
                                               int E, int epw) {
    __shared__ float Wt[64 * 64];
    for (int i = threadIdx.x; i < 4096; i += 256) {
        int c = i >> 6, f = i & 63;
        Wt[f * 64 + c] = W[i];
    }
    __syncthreads();

    int wave = blockIdx.x * 4 + (threadIdx.x >> 6);
    int lane = threadIdx.x & 63;
    long e0 = (long)wave * epw;
    if (e0 >= E) return;
    long e1 = e0 + epw; if (e1 > E) e1 = E;

    int cur = erow[e0];
    float acc = 0.f;
    for (long e = e0; e < e1; ++e) {
        int r = erow[e];
        int c = ecol[e];
        float v = evalv[e];
        float g = feat[((size_t)c << 6) | lane];
        if (r != cur) {
            float res = 0.f;
#pragma unroll
            for (int f = 0; f < 64; ++f)
                res += __shfl(acc, f, 64) * Wt[f * 64 + lane];
            atomicAdd(out + ((size_t)cur << 6) + lane, res);
            acc = 0.f;
            cur = r;
        }
        acc += v * g;
    }
    {
        float res = 0.f;
#pragma unroll
        for (int f = 0; f < 64; ++f)
            res += __shfl(acc, f, 64) * Wt[f * 64 + lane];
        atomicAdd(out + ((size_t)cur << 6) + lane, res);
    }
}

extern "C" void kernel_launch(void* const* d_in, const int* in_sizes, int n_in,
                              void* d_out, int out_size, void* d_ws, size_t ws_size,
                              hipStream_t stream) {
    const float* feat  = (const float*)d_in[0];
    const int*   erow  = (const int*)d_in[1];
    const int*   ecol  = (const int*)d_in[2];
    const float* evalv = (const float*)d_in[3];
    const float* W     = (const float*)d_in[4];
    const float* bias  = (const float*)d_in[5];
    float* out = (float*)d_out;

    int N = in_sizes[0] / 64;
    int E = in_sizes[1];

    size_t need = (size_t)N * 64 * sizeof(unsigned short);
    if (ws_size >= need) {
        unsigned short* G = (unsigned short*)d_ws;
        int tiles = (N + 15) / 16;
        int gblocks = (tiles + 3) / 4;
        long total4 = (long)N * 16;
        int iblocks = (int)((total4 + 255) / 256);
        k_setup<<<gblocks + iblocks, 256, 0, stream>>>(feat, W, bias, G, out, N, gblocks);

        // 4 feature-groups x (E/256) waves; 8-block octets map 2 blocks to
        // each XCD pair so every fg's plane stays in one XCD pair's L2.
        int nwpf = (E + 255) / 256;        // waves per feature-group
        int bpf  = (nwpf + 3) / 4;         // blocks per feature-group
        int noct = (bpf + 1) / 2;          // groups of 8 blocks
        k_spmm<<<noct * 8, 256, 0, stream>>>(G, erow, ecol, evalv, bias, out, E, N);
    } else {
        long total4 = (long)N * 16;
        k_init<<<(int)((total4 + 255) / 256), 256, 0, stream>>>(bias, out, total4);
        int epw = (E + 8191) / 8192;
        if (epw < 32) epw = 32;
        int nwaves = (E + epw - 1) / epw;
        int nblocks = (nwaves + 3) / 4;
        k_fused<<<nblocks, 256, 0, stream>>>(feat, erow, ecol, evalv, W, out, E, epw);
    }
}

// Round 4
// 166.894 us; speedup vs baseline: 1.1224x; 1.0408x over previous
//
#include <hip/hip_runtime.h>
#include <hip/hip_bf16.h>

typedef __attribute__((ext_vector_type(8))) short short8;
typedef __attribute__((ext_vector_type(4))) float f32x4;

__device__ __forceinline__ unsigned short f2bf(float x) {
    unsigned int u = __float_as_uint(x);
    unsigned int lsb = (u >> 16) & 1u;
    u += 0x7fffu + lsb;                    // round-to-nearest-even
    return (unsigned short)(u >> 16);
}

__device__ __forceinline__ short8 pack8(f32x4 a, f32x4 b) {
    short8 r;
    r[0] = (short)f2bf(a.x); r[1] = (short)f2bf(a.y);
    r[2] = (short)f2bf(a.z); r[3] = (short)f2bf(a.w);
    r[4] = (short)f2bf(b.x); r[5] = (short)f2bf(b.y);
    r[6] = (short)f2bf(b.z); r[7] = (short)f2bf(b.w);
    return r;
}

// Standalone init (fallback path): out[n][c] = bias[c]
__global__ __launch_bounds__(256) void k_init(const float* __restrict__ bias,
                                              float* __restrict__ out, long total4) {
    long i4 = (long)blockIdx.x * 256 + threadIdx.x;
    if (i4 < total4) {
        const f32x4* b4 = (const f32x4*)bias;
        ((f32x4*)out)[i4] = b4[i4 & 15];
    }
}

// Fused: blocks [0,gblocks) compute G = (feat @ W.T) in bf16 via MFMA;
// blocks [gblocks, ...) broadcast bias into out. G is FLAT [N][64] bf16
// (R4 reverted the R2/R3 plane split: locality is not the lever, line
// economy + in-flight depth is).
// NOTE: out init must be a PLAIN store — NT store streamed it to HBM and made
// every later atomic flush RMW against HBM (R4: WRITE_SIZE doubled, +22 us).
__global__ __launch_bounds__(256) void k_setup(const float* __restrict__ feat,
                                               const float* __restrict__ W,
                                               const float* __restrict__ bias,
                                               unsigned short* __restrict__ G,
                                               float* __restrict__ out,
                                               int N, int gblocks) {
    if ((int)blockIdx.x >= gblocks) {
        long i4 = (long)(blockIdx.x - gblocks) * 256 + threadIdx.x;
        long total4 = (long)N * 16;            // N*64 floats / 4
        if (i4 < total4) {
            const f32x4* b4 = (const f32x4*)bias;
            ((f32x4*)out)[i4] = b4[i4 & 15];   // plain store: stay dirty in L2
        }
        return;
    }

    int wave = blockIdx.x * 4 + (threadIdx.x >> 6);
    int lane = threadIdx.x & 63;
    int m0 = wave * 16;
    if (m0 >= N) return;
    int n = lane & 15;
    int quad = lane >> 4;

    // B fragments: B[k][c0+n] = W[c0+n][k]; k = ks*32 + quad*8 + j
    short8 bf[4][2];
#pragma unroll
    for (int ct = 0; ct < 4; ++ct)
#pragma unroll
        for (int ks = 0; ks < 2; ++ks) {
            const f32x4* wp = (const f32x4*)(W + (size_t)(ct * 16 + n) * 64 + ks * 32 + quad * 8);
            f32x4 w0 = wp[0];
            f32x4 w1 = wp[1];
            bf[ct][ks] = pack8(w0, w1);
        }

    // A fragments: A[m0+n][k]  (NT load: feat read exactly once)
    int mrow = m0 + n; if (mrow >= N) mrow = N - 1;
    short8 af[2];
#pragma unroll
    for (int ks = 0; ks < 2; ++ks) {
        const f32x4* ap = (const f32x4*)(feat + (size_t)mrow * 64 + ks * 32 + quad * 8);
        f32x4 a0 = __builtin_nontemporal_load(ap);
        f32x4 a1 = __builtin_nontemporal_load(ap + 1);
        af[ks] = pack8(a0, a1);
    }

    f32x4 acc[4];
#pragma unroll
    for (int ct = 0; ct < 4; ++ct) {
        acc[ct] = (f32x4){0.f, 0.f, 0.f, 0.f};
#pragma unroll
        for (int ks = 0; ks < 2; ++ks)
            acc[ct] = __builtin_amdgcn_mfma_f32_16x16x32_bf16(af[ks], bf[ct][ks], acc[ct], 0, 0, 0);
    }

    // D layout: col = lane&15 (=n), row = quad*4 + reg. Plain stores: G is
    // re-read by k_spmm, keep it in L2/L3.
#pragma unroll
    for (int ct = 0; ct < 4; ++ct)
#pragma unroll
        for (int r = 0; r < 4; ++r) {
            int rowm = m0 + quad * 4 + r;
            if (rowm < N)
                G[(size_t)rowm * 64 + ct * 16 + n] = f2bf(acc[ct][r]);
        }
}

// SpMM: out[row] += val * G[col]. Sorted rows. 256 edges/wave.
// R12 model (from R0-R3 measurements): gather throughput = per-CU line-fill
// BW wall ~9.5 B/cy/CU (same as streaming share), reached only when enough
// 64B line-fills are in flight (R1: deep in-flight hit 0.147 lines/cy/CU
// unlocalized; R0's 32-in-flight sat at 0.078). Lines are the currency:
// R0 = 3.2M fully-used lines (2/edge); R1/R2/R3 = 6.4M half-used.
// This kernel: full-line economy AND deep in-flight.
//  - Pair gathers: lanes 0-31 load edge k's full 128B row as dwords,
//    lanes 32-63 edge k+1's -> 4 fully-used lines / instruction.
//  - 16-instr groups issued 2 ahead (32-48 instrs = 128-192 lines in
//    flight per wave, above the latency*BW product).
//  - Cols/vals broadcast per half-wave via ds_bpermute (no readlane
//    cascade); ballot boundary masks in SGPRs select a branch-free
//    interior fast path (avg row len 16 -> ~88% of pairs).
//  - Flush: shfl_xor(32) half-reduce, lanes 0-31 write float2 (interior
//    rows plain-store bias+acc; first/last possibly-shared rows atomic).
__global__ __launch_bounds__(256) void k_spmm(const unsigned short* __restrict__ G,
                                              const int* __restrict__ erow,
                                              const int* __restrict__ ecol,
                                              const float* __restrict__ evalv,
                                              const float* __restrict__ bias,
                                              float* __restrict__ out, int E) {
    int wave = blockIdx.x * 4 + (threadIdx.x >> 6);
    int lane = threadIdx.x & 63;
    long base0 = (long)wave * 256;
    if (base0 >= E) return;

    int l5 = lane & 31;
    bool hi = lane >= 32;                   // half-wave = edge slot in pair
    unsigned voff = (unsigned)l5 * 4u;      // byte offset of lane's dword in 128B row
    int vb4 = hi ? 4 : 0;                   // bpermute byte offset: edge-in-pair
    const char* Gb = (const char*)G;
    float2 b2 = ((const float2*)bias)[l5];  // feats (2*l5, 2*l5+1)

    float acc0 = 0.f, acc1 = 0.f;
    bool first = true;                      // first row may be shared w/ prev wave
    int cur;

    auto flush_atomic = [&]() {
        float t0 = acc0 + __shfl_xor(acc0, 32);
        float t1 = acc1 + __shfl_xor(acc1, 32);
        if (lane < 32) {
            float* p = out + ((size_t)(unsigned)cur << 6) + (unsigned)(l5 * 2);
            atomicAdd(p, t0);
            atomicAdd(p + 1, t1);
        }
        acc0 = 0.f; acc1 = 0.f;
    };
    auto flush = [&]() {
        if (first) { flush_atomic(); first = false; return; }
        float t0 = acc0 + __shfl_xor(acc0, 32);
        float t1 = acc1 + __shfl_xor(acc1, 32);
        if (lane < 32) {
            float* p = out + ((size_t)(unsigned)cur << 6) + (unsigned)(l5 * 2);
            float2 o; o.x = b2.x + t0; o.y = b2.y + t1;
            *(float2*)p = o;
        }
        acc0 = 0.f; acc1 = 0.f;
    };

    if (base0 + 256 <= E) {
        // ---- fast path: full 256-edge segment ----
        long i0 = base0 + lane;
        int rv[4], cv[4], vvv[4];
#pragma unroll
        for (int c = 0; c < 4; ++c) {
            rv[c]  = __builtin_nontemporal_load(erow + i0 + 64 * c);
            cv[c]  = __builtin_nontemporal_load(ecol + i0 + 64 * c);
            vvv[c] = __builtin_nontemporal_load((const int*)evalv + i0 + 64 * c);
        }
        cur = __builtin_amdgcn_readlane(rv[0], 0);

        // boundary masks: bit e of bm[c] = row[e] != row[e+1] within chunk c;
        // bit 63 = boundary between chunk c and c+1 (forced at segment end)
        unsigned long long bm[4];
#pragma unroll
        for (int c = 0; c < 4; ++c) {
            int rn = __shfl_down(rv[c], 1);
            unsigned long long m = __ballot(rv[c] != rn) & 0x7fffffffffffffffULL;
            int r63 = __builtin_amdgcn_readlane(rv[c], 63);
            int n0  = (c < 3) ? __builtin_amdgcn_readlane(rv[c + 1], 0) : (r63 + 1);
            if (r63 != n0) m |= 0x8000000000000000ULL;
            bm[c] = m;
        }

        unsigned gbuf[3][16];               // 3-slot rolling buffer of pair-gathers

#define SPMM_ISSUE(GI, SLOT) do {                                              \
    _Pragma("unroll")                                                          \
    for (int k_ = 0; k_ < 16; ++k_) {                                          \
        const int p_ = (GI) * 16 + k_;                                         \
        const int c_ = p_ >> 5;                                                \
        const int pj_ = p_ & 31;                                               \
        int idx_ = vb4 + 8 * pj_;                                              \
        int colv_ = __builtin_amdgcn_ds_bpermute(idx_, cv[c_]);                \
        unsigned off_ = ((unsigned)colv_ << 7) + voff;                         \
        gbuf[SLOT][k_] = *(const unsigned*)(Gb + off_);                        \
    } } while (0)

        // prologue: two groups in flight before first consume
        SPMM_ISSUE(0, 0);
        SPMM_ISSUE(1, 1);

#pragma unroll
        for (int g = 0; g < 8; ++g) {
            if (g < 6) SPMM_ISSUE(g + 2, (g + 2) % 3);
            __builtin_amdgcn_sched_barrier(0);   // keep issue ahead of consume

#pragma unroll
            for (int k = 0; k < 16; ++k) {
                const int p  = g * 16 + k;       // pair index 0..127
                const int c  = p >> 5;           // chunk
                const int pj = p & 31;           // pair within chunk
                int idx = vb4 + 8 * pj;
                float vs = __int_as_float(__builtin_amdgcn_ds_bpermute(idx, vvv[c]));
                unsigned u = gbuf[g % 3][k];
                float flo = __uint_as_float(u << 16);
                float fhi = __uint_as_float(u & 0xffff0000u);
                // A = boundary before pair; B = boundary inside pair
                int A = (pj > 0) ? (int)((bm[c] >> (2 * pj - 1)) & 1ULL)
                      : (c > 0)  ? (int)((bm[c - 1] >> 63) & 1ULL) : 0;
                int B = (int)((bm[c] >> (2 * pj)) & 1ULL);
                if ((A | B) == 0) {
                    acc0 = fmaf(vs, flo, acc0);
                    acc1 = fmaf(vs, fhi, acc1);
                } else if (B == 0) {             // new row starts at this pair
                    flush();
                    cur = __builtin_amdgcn_readlane(rv[c], 2 * pj);
                    acc0 = fmaf(vs, flo, acc0);
                    acc1 = fmaf(vs, fhi, acc1);
                } else {                          // boundary inside the pair
                    if (A) {
                        flush();
                        cur = __builtin_amdgcn_readlane(rv[c], 2 * pj);
                    }
                    float vsl = hi ? 0.f : vs;   // lo edge belongs to cur
                    acc0 = fmaf(vsl, flo, acc0);
                    acc1 = fmaf(vsl, fhi, acc1);
                    flush();
                    cur = __builtin_amdgcn_readlane(rv[c], 2 * pj + 1);
                    float vsh = hi ? vs : 0.f;   // hi edge starts the new row
                    acc0 = fmaf(vsh, flo, acc0);
                    acc1 = fmaf(vsh, fhi, acc1);
                }
            }
        }
#undef SPMM_ISSUE
    } else {
        // ---- tail path: generic 2-edges-at-a-time loop, same acc layout ----
        cur = erow[base0];
        for (long e = base0; e < (long)E; e += 2) {
            int r0 = erow[e];
            int c0 = ecol[e];
            float v0 = evalv[e];
            bool has1 = (e + 1 < (long)E);
            int r1 = has1 ? erow[e + 1] : r0;
            int c1 = has1 ? ecol[e + 1] : c0;
            float v1 = has1 ? evalv[e + 1] : 0.f;
            int csel = hi ? c1 : c0;
            float vs = hi ? v1 : v0;
            unsigned off = ((unsigned)csel << 7) + voff;
            unsigned u = *(const unsigned*)(Gb + off);
            float flo = __uint_as_float(u << 16);
            float fhi = __uint_as_float(u & 0xffff0000u);
            if (r0 != cur) { flush(); cur = r0; }
            if (r1 == r0) {
                acc0 = fmaf(vs, flo, acc0);
                acc1 = fmaf(vs, fhi, acc1);
            } else {
                float vsl = hi ? 0.f : vs;
                acc0 = fmaf(vsl, flo, acc0);
                acc1 = fmaf(vsl, fhi, acc1);
                flush();
                cur = r1;
                float vsh = hi ? vs : 0.f;
                acc0 = fmaf(vsh, flo, acc0);
                acc1 = fmaf(vsh, fhi, acc1);
            }
        }
    }

    // last row may be shared with the next wave -> always atomic
    flush_atomic();
}

// Fallback if ws too small: fused f32 gather + shfl transform at flush.
__global__ __launch_bounds__(256) void k_fused(const float* __restrict__ feat,
                                               const int* __restrict__ erow,
                                               const int* __restrict__ ecol,
                                               const float* __restrict__ evalv,
                                               const float* __restrict__ W,
                                               float* __restrict__ out,
                                               int E, int epw) {
    __shared__ float Wt[64 * 64];
    for (int i = threadIdx.x; i < 4096; i += 256) {
        int c = i >> 6, f = i & 63;
        Wt[f * 64 + c] = W[i];
    }
    __syncthreads();

    int wave = blockIdx.x * 4 + (threadIdx.x >> 6);
    int lane = threadIdx.x & 63;
    long e0 = (long)wave * epw;
    if (e0 >= E) return;
    long e1 = e0 + epw; if (e1 > E) e1 = E;

    int cur = erow[e0];
    float acc = 0.f;
    for (long e = e0; e < e1; ++e) {
        int r = erow[e];
        int c = ecol[e];
        float v = evalv[e];
        float g = feat[((size_t)c << 6) | lane];
        if (r != cur) {
            float res = 0.f;
#pragma unroll
            for (int f = 0; f < 64; ++f)
                res += __shfl(acc, f, 64) * Wt[f * 64 + lane];
            atomicAdd(out + ((size_t)cur << 6) + lane, res);
            acc = 0.f;
            cur = r;
        }
        acc += v * g;
    }
    {
        float res = 0.f;
#pragma unroll
        for (int f = 0; f < 64; ++f)
            res += __shfl(acc, f, 64) * Wt[f * 64 + lane];
        atomicAdd(out + ((size_t)cur << 6) + lane, res);
    }
}

extern "C" void kernel_launch(void* const* d_in, const int* in_sizes, int n_in,
                              void* d_out, int out_size, void* d_ws, size_t ws_size,
                              hipStream_t stream) {
    const float* feat  = (const float*)d_in[0];
    const int*   erow  = (const int*)d_in[1];
    const int*   ecol  = (const int*)d_in[2];
    const float* evalv = (const float*)d_in[3];
    const float* W     = (const float*)d_in[4];
    const float* bias  = (const float*)d_in[5];
    float* out = (float*)d_out;

    int N = in_sizes[0] / 64;
    int E = in_sizes[1];

    size_t need = (size_t)N * 64 * sizeof(unsigned short);
    if (ws_size >= need) {
        unsigned short* G = (unsigned short*)d_ws;
        int tiles = (N + 15) / 16;
        int gblocks = (tiles + 3) / 4;
        long total4 = (long)N * 16;
        int iblocks = (int)((total4 + 255) / 256);
        k_setup<<<gblocks + iblocks, 256, 0, stream>>>(feat, W, bias, G, out, N, gblocks);

        int nwaves = (E + 255) / 256;            // 256 edges/wave
        int nblocks = (nwaves + 3) / 4;
        k_spmm<<<nblocks, 256, 0, stream>>>(G, erow, ecol, evalv, bias, out, E);
    } else {
        long total4 = (long)N * 16;
        k_init<<<(int)((total4 + 255) / 256), 256, 0, stream>>>(bias, out, total4);
        int epw = (E + 8191) / 8192;
        if (epw < 32) epw = 32;
        int nwaves = (E + epw - 1) / epw;
        int nblocks = (nwaves + 3) / 4;
        k_fused<<<nblocks, 256, 0, stream>>>(feat, erow, ecol, evalv, W, out, E, epw);
    }
}

// Round 5
// 164.782 us; speedup vs baseline: 1.1367x; 1.0128x over previous
//
#include <hip/hip_runtime.h>
#include <hip/hip_bf16.h>

typedef __attribute__((ext_vector_type(8))) short short8;
typedef __attribute__((ext_vector_type(4))) float f32x4;

__device__ __forceinline__ unsigned short f2bf(float x) {
    unsigned int u = __float_as_uint(x);
    unsigned int lsb = (u >> 16) & 1u;
    u += 0x7fffu + lsb;                    // round-to-nearest-even
    return (unsigned short)(u >> 16);
}

__device__ __forceinline__ short8 pack8(f32x4 a, f32x4 b) {
    short8 r;
    r[0] = (short)f2bf(a.x); r[1] = (short)f2bf(a.y);
    r[2] = (short)f2bf(a.z); r[3] = (short)f2bf(a.w);
    r[4] = (short)f2bf(b.x); r[5] = (short)f2bf(b.y);
    r[6] = (short)f2bf(b.z); r[7] = (short)f2bf(b.w);
    return r;
}

// Standalone init (fallback path): out[n][c] = bias[c]
__global__ __launch_bounds__(256) void k_init(const float* __restrict__ bias,
                                              float* __restrict__ out, long total4) {
    long i4 = (long)blockIdx.x * 256 + threadIdx.x;
    if (i4 < total4) {
        const f32x4* b4 = (const f32x4*)bias;
        ((f32x4*)out)[i4] = b4[i4 & 15];
    }
}

// Fused: blocks [0,gblocks) compute G = (feat @ W.T) in bf16 via MFMA;
// blocks [gblocks, ...) broadcast bias into out. G is FLAT [N][64] bf16.
// NOTE: out init must be a PLAIN store — NT store streamed it to HBM and made
// every later atomic flush RMW against HBM (R4: WRITE_SIZE doubled, +22 us).
__global__ __launch_bounds__(256) void k_setup(const float* __restrict__ feat,
                                               const float* __restrict__ W,
                                               const float* __restrict__ bias,
                                               unsigned short* __restrict__ G,
                                               float* __restrict__ out,
                                               int N, int gblocks) {
    if ((int)blockIdx.x >= gblocks) {
        long i4 = (long)(blockIdx.x - gblocks) * 256 + threadIdx.x;
        long total4 = (long)N * 16;            // N*64 floats / 4
        if (i4 < total4) {
            const f32x4* b4 = (const f32x4*)bias;
            ((f32x4*)out)[i4] = b4[i4 & 15];   // plain store: stay dirty in L2
        }
        return;
    }

    int wave = blockIdx.x * 4 + (threadIdx.x >> 6);
    int lane = threadIdx.x & 63;
    int m0 = wave * 16;
    if (m0 >= N) return;
    int n = lane & 15;
    int quad = lane >> 4;

    // B fragments: B[k][c0+n] = W[c0+n][k]; k = ks*32 + quad*8 + j
    short8 bf[4][2];
#pragma unroll
    for (int ct = 0; ct < 4; ++ct)
#pragma unroll
        for (int ks = 0; ks < 2; ++ks) {
            const f32x4* wp = (const f32x4*)(W + (size_t)(ct * 16 + n) * 64 + ks * 32 + quad * 8);
            f32x4 w0 = wp[0];
            f32x4 w1 = wp[1];
            bf[ct][ks] = pack8(w0, w1);
        }

    // A fragments: A[m0+n][k]  (NT load: feat read exactly once)
    int mrow = m0 + n; if (mrow >= N) mrow = N - 1;
    short8 af[2];
#pragma unroll
    for (int ks = 0; ks < 2; ++ks) {
        const f32x4* ap = (const f32x4*)(feat + (size_t)mrow * 64 + ks * 32 + quad * 8);
        f32x4 a0 = __builtin_nontemporal_load(ap);
        f32x4 a1 = __builtin_nontemporal_load(ap + 1);
        af[ks] = pack8(a0, a1);
    }

    f32x4 acc[4];
#pragma unroll
    for (int ct = 0; ct < 4; ++ct) {
        acc[ct] = (f32x4){0.f, 0.f, 0.f, 0.f};
#pragma unroll
        for (int ks = 0; ks < 2; ++ks)
            acc[ct] = __builtin_amdgcn_mfma_f32_16x16x32_bf16(af[ks], bf[ct][ks], acc[ct], 0, 0, 0);
    }

    // D layout: col = lane&15 (=n), row = quad*4 + reg. Plain stores: G is
    // re-read by k_spmm, keep it in L2/L3.
#pragma unroll
    for (int ct = 0; ct < 4; ++ct)
#pragma unroll
        for (int r = 0; r < 4; ++r) {
            int rowm = m0 + quad * 4 + r;
            if (rowm < N)
                G[(size_t)rowm * 64 + ct * 16 + n] = f2bf(acc[ct][r]);
        }
}

// SpMM: out[row] += val * G[col]. Sorted rows. 256 edges/wave, TWO passes.
// R13 model (R0-R4 measurements): useful-byte gather rate flat at 2.4-3.0
// TB/s in every structure, BUT line-TOUCH rate doubles (0.073 -> 0.138
// lines/cy/CU) when each edge's data is fetched as independent single-line
// streams (R2/R3 32B plane segments) instead of one 128B two-line row
// (R0/R1/R4). R2/R3 wasted half of each line (32B rows). This kernel takes
// the untested cell: SINGLE FULL 64B LINE per edge-request at the plane-
// round instruction shape. Flat G already has 64B half-rows: line 2c+fg of
// G = features [32fg,32fg+32) of col c. Pass fg in {0,1} handles feature
// half fg for ALL edges (XCD-quad partitioned: fg = (blockIdx&7)>>2 so each
// XCD's L2 works on a 6.4 MB half of G). Per instruction: 4 edges x 16
// lanes x dword = 4 random fully-used lines (R3's proven shape). Gathers
// issued in 8-pack groups, 2 groups ahead (3-slot rolling buffer). Ballot
// boundary masks in SGPRs -> branch-free interior fast path; R3's validated
// slow path at row boundaries. Flush: shfl_xor(16/32) quarter-reduce, lanes
// 0-15 write float2 (features fg*32+2fs..+1): plain bias+acc store interior,
// atomicAdd for first/last possibly-shared rows. fg halves touch disjoint
// 64B lines of out -> no cross-pass interference.
__global__ __launch_bounds__(256) void k_spmm(const unsigned short* __restrict__ G,
                                              const int* __restrict__ erow,
                                              const int* __restrict__ ecol,
                                              const float* __restrict__ evalv,
                                              const float* __restrict__ bias,
                                              float* __restrict__ out, int E) {
    int b = blockIdx.x;
    int fg  = (b & 7) >> 2;                 // XCD quad -> feature half
    int sub = (b >> 3) * 4 + (b & 3);       // block index within this fg
    int wavein = threadIdx.x >> 6;
    int lane = threadIdx.x & 63;
    long base0 = ((long)sub * 4 + wavein) * 256;
    if (base0 >= E) return;

    int q  = lane >> 4;                     // edge slot within 4-edge pack
    int fs = lane & 15;                     // feature-dword within 32-feat half
    int vq4 = q << 2;                       // bpermute byte base for quarter
    unsigned voff = (unsigned)fs * 4u;      // byte offset within 64B half-row
    const char* Gb = (const char*)G + ((unsigned)fg << 6);
    float2 b2 = ((const float2*)bias)[fg * 16 + fs];

    float acc0 = 0.f, acc1 = 0.f;
    bool first = true;                      // first row may be shared w/ prev wave
    int cur;

    auto flush_atomic = [&]() {
        float t0 = acc0 + __shfl_xor(acc0, 16);
        float t1 = acc1 + __shfl_xor(acc1, 16);
        t0 += __shfl_xor(t0, 32);
        t1 += __shfl_xor(t1, 32);
        if (lane < 16) {
            float* p = out + ((size_t)(unsigned)cur << 6) + (unsigned)(fg * 32 + fs * 2);
            atomicAdd(p, t0);
            atomicAdd(p + 1, t1);
        }
        acc0 = 0.f; acc1 = 0.f;
    };
    auto flush = [&]() {
        if (first) { flush_atomic(); first = false; return; }
        float t0 = acc0 + __shfl_xor(acc0, 16);
        float t1 = acc1 + __shfl_xor(acc1, 16);
        t0 += __shfl_xor(t0, 32);
        t1 += __shfl_xor(t1, 32);
        if (lane < 16) {
            float* p = out + ((size_t)(unsigned)cur << 6) + (unsigned)(fg * 32 + fs * 2);
            float2 o; o.x = b2.x + t0; o.y = b2.y + t1;
            *(float2*)p = o;
        }
        acc0 = 0.f; acc1 = 0.f;
    };

    if (base0 + 256 <= E) {
        // ---- fast path: full 256-edge segment ----
        long i0 = base0 + lane;
        int rv[4], cv[4], vvv[4];
#pragma unroll
        for (int c = 0; c < 4; ++c) {
            rv[c]  = __builtin_nontemporal_load(erow + i0 + 64 * c);
            cv[c]  = __builtin_nontemporal_load(ecol + i0 + 64 * c);
            vvv[c] = __builtin_nontemporal_load((const int*)evalv + i0 + 64 * c);
        }
        cur = __builtin_amdgcn_readlane(rv[0], 0);

        // boundary masks: bit e of bm[c] = row[e] != row[e+1] within chunk c;
        // bit 63 = boundary between chunk c and c+1 (forced at segment end)
        unsigned long long bm[4];
#pragma unroll
        for (int c = 0; c < 4; ++c) {
            int rn = __shfl_down(rv[c], 1);
            unsigned long long m = __ballot(rv[c] != rn) & 0x7fffffffffffffffULL;
            int r63 = __builtin_amdgcn_readlane(rv[c], 63);
            int n0  = (c < 3) ? __builtin_amdgcn_readlane(rv[c + 1], 0) : (r63 + 1);
            if (r63 != n0) m |= 0x8000000000000000ULL;
            bm[c] = m;
        }

        unsigned gbuf[3][8];                // 3-slot rolling buffer of line-gathers

#define SPMM_ISSUE(GI, SLOT) do {                                              \
    _Pragma("unroll")                                                          \
    for (int k_ = 0; k_ < 8; ++k_) {                                           \
        const int p_  = (GI) * 8 + k_;      /* pack index 0..63 */             \
        const int c_  = p_ >> 4;            /* chunk */                        \
        const int pj_ = p_ & 15;            /* pack within chunk */            \
        int idx_ = vq4 + 16 * pj_;                                             \
        int colv_ = __builtin_amdgcn_ds_bpermute(idx_, cv[c_]);                \
        unsigned off_ = ((unsigned)colv_ << 7) + voff;                         \
        gbuf[SLOT][k_] = *(const unsigned*)(Gb + off_);                        \
    } } while (0)

        // prologue: two groups (64 lines) in flight before first consume
        SPMM_ISSUE(0, 0);
        SPMM_ISSUE(1, 1);

#pragma unroll
        for (int g = 0; g < 8; ++g) {
            if (g < 6) SPMM_ISSUE(g + 2, (g + 2) % 3);
            __builtin_amdgcn_sched_barrier(0);   // keep issue ahead of consume

#pragma unroll
            for (int k = 0; k < 8; ++k) {
                const int p  = g * 8 + k;        // pack index 0..63
                const int c  = p >> 4;           // chunk
                const int pj = p & 15;           // pack within chunk
                const int i4 = pj * 4;           // first edge-lane of pack
                int idx = vq4 + i4 * 4;
                float vs = __int_as_float(__builtin_amdgcn_ds_bpermute(idx, vvv[c]));
                unsigned u = gbuf[g % 3][k];
                float flo = __uint_as_float(u << 16);
                float fhi = __uint_as_float(u & 0xffff0000u);
                bool slow = (pj == 0) ? ((c > 0 && ((bm[c - 1] >> 63) & 1ULL)) || (bm[c] & 7ULL) != 0)
                                      : (((bm[c] >> (4 * pj - 1)) & 0xFULL) != 0);
                if (!slow) {
                    acc0 = fmaf(vs, flo, acc0);
                    acc1 = fmaf(vs, fhi, acc1);
                } else {
                    int r0 = __builtin_amdgcn_readlane(rv[c], i4);
                    int r3 = __builtin_amdgcn_readlane(rv[c], i4 + 3);
                    if (r0 == r3) {
                        if (r0 != cur) { flush(); cur = r0; }
                        acc0 = fmaf(vs, flo, acc0);
                        acc1 = fmaf(vs, fhi, acc1);
                    } else {
                        int rowsv = __builtin_amdgcn_ds_bpermute(idx, rv[c]);
                        int r1 = __builtin_amdgcn_readlane(rv[c], i4 + 1);
                        int r2 = __builtin_amdgcn_readlane(rv[c], i4 + 2);
                        int rr = r0;
                        while (true) {
                            if (rr != cur) { flush(); cur = rr; }
                            float vm = (rowsv == rr) ? vs : 0.f;
                            acc0 = fmaf(vm, flo, acc0);
                            acc1 = fmaf(vm, fhi, acc1);
                            if (rr == r3) break;
                            rr = (r1 > rr) ? r1 : ((r2 > rr) ? r2 : r3);
                        }
                    }
                }
            }
        }
#undef SPMM_ISSUE
    } else {
        // ---- tail path: generic per-edge loop (quarter 0 accumulates) ----
        cur = erow[base0];
        for (long e = base0; e < (long)E; ++e) {
            int r = erow[e];
            int c = ecol[e];
            float v = evalv[e];
            unsigned u = *(const unsigned*)(Gb + (((unsigned)c << 7) + voff));
            float flo = __uint_as_float(u << 16);
            float fhi = __uint_as_float(u & 0xffff0000u);
            if (r != cur) { flush(); cur = r; }
            float vm = (q == 0) ? v : 0.f;
            acc0 = fmaf(vm, flo, acc0);
            acc1 = fmaf(vm, fhi, acc1);
        }
    }

    // last row may be shared with the next wave -> always atomic
    flush_atomic();
}

// Fallback if ws too small: fused f32 gather + shfl transform at flush.
__global__ __launch_bounds__(256) void k_fused(const float* __restrict__ feat,
                                               const int* __restrict__ erow,
                                               const int* __restrict__ ecol,
                                               const float* __restrict__ evalv,
                                               const float* __restrict__ W,
                                               float* __restrict__ out,
                                               int E, int epw) {
    __shared__ float Wt[64 * 64];
    for (int i = threadIdx.x; i < 4096; i += 256) {
        int c = i >> 6, f = i & 63;
        Wt[f * 64 + c] = W[i];
    }
    __syncthreads();

    int wave = blockIdx.x * 4 + (threadIdx.x >> 6);
    int lane = threadIdx.x & 63;
    long e0 = (long)wave * epw;
    if (e0 >= E) return;
    long e1 = e0 + epw; if (e1 > E) e1 = E;

    int cur = erow[e0];
    float acc = 0.f;
    for (long e = e0; e < e1; ++e) {
        int r = erow[e];
        int c = ecol[e];
        float v = evalv[e];
        float g = feat[((size_t)c << 6) | lane];
        if (r != cur) {
            float res = 0.f;
#pragma unroll
            for (int f = 0; f < 64; ++f)
                res += __shfl(acc, f, 64) * Wt[f * 64 + lane];
            atomicAdd(out + ((size_t)cur << 6) + lane, res);
            acc = 0.f;
            cur = r;
        }
        acc += v * g;
    }
    {
        float res = 0.f;
#pragma unroll
        for (int f = 0; f < 64; ++f)
            res += __shfl(acc, f, 64) * Wt[f * 64 + lane];
        atomicAdd(out + ((size_t)cur << 6) + lane, res);
    }
}

extern "C" void kernel_launch(void* const* d_in, const int* in_sizes, int n_in,
                              void* d_out, int out_size, void* d_ws, size_t ws_size,
                              hipStream_t stream) {
    const float* feat  = (const float*)d_in[0];
    const int*   erow  = (const int*)d_in[1];
    const int*   ecol  = (const int*)d_in[2];
    const float* evalv = (const float*)d_in[3];
    const float* W     = (const float*)d_in[4];
    const float* bias  = (const float*)d_in[5];
    float* out = (float*)d_out;

    int N = in_sizes[0] / 64;
    int E = in_sizes[1];

    size_t need = (size_t)N * 64 * sizeof(unsigned short);
    if (ws_size >= need) {
        unsigned short* G = (unsigned short*)d_ws;
        int tiles = (N + 15) / 16;
        int gblocks = (tiles + 3) / 4;
        long total4 = (long)N * 16;
        int iblocks = (int)((total4 + 255) / 256);
        k_setup<<<gblocks + iblocks, 256, 0, stream>>>(feat, W, bias, G, out, N, gblocks);

        // 2 feature-halves x (E/256) waves; octets of 8 blocks give 4 blocks
        // to each XCD quad, so each quad's L2 works one 6.4 MB half of G.
        int nwpf = (E + 255) / 256;        // segments (waves) per feature-half
        int bpf  = (nwpf + 3) / 4;         // blocks per feature-half
        int noct = (bpf + 3) / 4;          // octets: 4 blocks per half each
        k_spmm<<<noct * 8, 256, 0, stream>>>(G, erow, ecol, evalv, bias, out, E);
    } else {
        long total4 = (long)N * 16;
        k_init<<<(int)((total4 + 255) / 256), 256, 0, stream>>>(bias, out, total4);
        int epw = (E + 8191) / 8192;
        if (epw < 32) epw = 32;
        int nwaves = (E + epw - 1) / epw;
        int nblocks = (nwaves + 3) / 4;
        k_fused<<<nblocks, 256, 0, stream>>>(feat, erow, ecol, evalv, W, out, E, epw);
    }
}